// Round 1
// baseline (536.340 us; speedup 1.0000x reference)
//
#include <hip/hip_runtime.h>

typedef unsigned short u16;
typedef __attribute__((ext_vector_type(8))) short bf16x8;
typedef __attribute__((ext_vector_type(4))) float f32x4;

__device__ __forceinline__ u16 f2bf(float f) {
  union { float f; unsigned u; } x; x.f = f;
  unsigned u = x.u;
  u += 0x7fffu + ((u >> 16) & 1u);
  return (u16)(u >> 16);
}

// ---------------- fp32 -> bf16 convert ----------------
__global__ __launch_bounds__(256) void cvt_f32_bf16(
    const float* __restrict__ src, u16* __restrict__ dst, int n4) {
  int i = blockIdx.x * blockDim.x + threadIdx.x;
  if (i < n4) {
    float4 f = reinterpret_cast<const float4*>(src)[i];
    ushort4 o;
    o.x = f2bf(f.x); o.y = f2bf(f.y); o.z = f2bf(f.z); o.w = f2bf(f.w);
    reinterpret_cast<ushort4*>(dst)[i] = o;
  }
}

// ---------------- shared GEMM core: C = A (Mx512) * W^T (512x512), bf16 in, f32 acc
#define BM 128
#define BN 128
#define BK 32
#define LDP 40  // padded LDS row stride (u16 units): banks (r*20)%32 -> only 2-way aliasing (free)

__device__ __forceinline__ void gemm_core(
    const u16* __restrict__ A, const u16* __restrict__ W,
    int mtile, int ntile, u16* lds_a, u16* lds_b,
    f32x4 acc[4][4], int tid)
{
  int lane = tid & 63;
  int w = tid >> 6;
  int wm = w >> 1, wn = w & 1;
  int ar = tid >> 2;        // 0..63
  int ac = (tid & 3) * 8;   // 0,8,16,24
  int lrow = lane & 15, lk = lane >> 4;

  for (int k0 = 0; k0 < 512; k0 += BK) {
    __syncthreads();
#pragma unroll
    for (int rr = 0; rr < BM; rr += 64) {
      int4 va = *reinterpret_cast<const int4*>(A + (mtile + ar + rr) * 512 + k0 + ac);
      *reinterpret_cast<int4*>(lds_a + (ar + rr) * LDP + ac) = va;
      int4 vb = *reinterpret_cast<const int4*>(W + (ntile + ar + rr) * 512 + k0 + ac);
      *reinterpret_cast<int4*>(lds_b + (ar + rr) * LDP + ac) = vb;
    }
    __syncthreads();
    bf16x8 af[4], bfr[4];
#pragma unroll
    for (int i = 0; i < 4; i++) {
      af[i]  = *reinterpret_cast<bf16x8*>(lds_a + (wm * 64 + i * 16 + lrow) * LDP + lk * 8);
      bfr[i] = *reinterpret_cast<bf16x8*>(lds_b + (wn * 64 + i * 16 + lrow) * LDP + lk * 8);
    }
#pragma unroll
    for (int i = 0; i < 4; i++)
#pragma unroll
      for (int j = 0; j < 4; j++)
        acc[i][j] = __builtin_amdgcn_mfma_f32_16x16x32_bf16(af[i], bfr[j], acc[i][j], 0, 0, 0);
  }
}

// ---------------- fused Q/K/V projection ----------------
// z=0: Q -> [B][H][S][64]; z=1: K -> [B][H][S][64]; z=2: V -> [B][H][64][S] (transposed)
__global__ __launch_bounds__(256) void proj_gemm(
    const u16* __restrict__ Xb, const u16* __restrict__ Wb,
    u16* __restrict__ Qb, u16* __restrict__ Kb, u16* __restrict__ Vt)
{
  __shared__ u16 lds_a[BM * LDP];
  __shared__ u16 lds_b[BN * LDP];
  int z = blockIdx.z;
  const u16* A = Xb + (size_t)z * (8192 * 512);
  const u16* W = Wb + (size_t)z * (512 * 512);
  f32x4 acc[4][4] = {};
  int mtile = blockIdx.x * BM, ntile = blockIdx.y * BN;
  gemm_core(A, W, mtile, ntile, lds_a, lds_b, acc, threadIdx.x);

  int lane = threadIdx.x & 63;
  int w = threadIdx.x >> 6;
  int wm = w >> 1, wn = w & 1;
  int lrow = lane & 15, lk = lane >> 4;
  u16* dst = (z == 0) ? Qb : (z == 1) ? Kb : Vt;
#pragma unroll
  for (int i = 0; i < 4; i++)
#pragma unroll
    for (int j = 0; j < 4; j++)
#pragma unroll
      for (int r = 0; r < 4; r++) {
        int m = mtile + wm * 64 + i * 16 + lk * 4 + r;
        int n = ntile + wn * 64 + j * 16 + lrow;
        u16 bv = f2bf(acc[i][j][r]);
        int b = m >> 12, s = m & 4095;
        int h = n >> 6, d = n & 63;
        if (z <= 1) dst[(((size_t)(b * 8 + h) * 4096 + s) * 64 + d)] = bv;
        else        dst[(((size_t)(b * 8 + h) * 64 + d) * 4096 + s)] = bv;
      }
}

// ---------------- output projection (fp32 out) ----------------
__global__ __launch_bounds__(256) void out_gemm(
    const u16* __restrict__ AO, const u16* __restrict__ Wo, float* __restrict__ out)
{
  __shared__ u16 lds_a[BM * LDP];
  __shared__ u16 lds_b[BN * LDP];
  f32x4 acc[4][4] = {};
  int mtile = blockIdx.x * BM, ntile = blockIdx.y * BN;
  gemm_core(AO, Wo, mtile, ntile, lds_a, lds_b, acc, threadIdx.x);

  int lane = threadIdx.x & 63;
  int w = threadIdx.x >> 6;
  int wm = w >> 1, wn = w & 1;
  int lrow = lane & 15, lk = lane >> 4;
#pragma unroll
  for (int i = 0; i < 4; i++)
#pragma unroll
    for (int j = 0; j < 4; j++)
#pragma unroll
      for (int r = 0; r < 4; r++) {
        int m = mtile + wm * 64 + i * 16 + lk * 4 + r;
        int n = ntile + wn * 64 + j * 16 + lrow;
        out[(size_t)m * 512 + n] = acc[i][j][r];
      }
}

// ---------------- flash attention ----------------
// grid: (S/64, B*H). 4 waves/block, each wave owns 16 query rows.
__global__ __launch_bounds__(256) void attn_kernel(
    const u16* __restrict__ Qb, const u16* __restrict__ Kb,
    const u16* __restrict__ Vt, const int* __restrict__ mask,
    u16* __restrict__ AO)
{
  __shared__ u16 p_lds[4][16][72];  // per-wave P tile, padded stride 72
  int tid = threadIdx.x;
  int lane = tid & 63;
  int w = tid >> 6;
  int bh = blockIdx.y;
  int b = bh >> 3, h = bh & 7;
  int q0 = blockIdx.x * 64;
  int lrow = lane & 15, lk = lane >> 4;

  // Q fragments for this wave's 16 rows (A layout: row=lane&15, k=(lane>>4)*8+j)
  const u16* Qp = Qb + ((size_t)bh * 4096 + q0 + w * 16) * 64;
  bf16x8 aq0 = *reinterpret_cast<const bf16x8*>(Qp + lrow * 64 + lk * 8);
  bf16x8 aq1 = *reinterpret_cast<const bf16x8*>(Qp + lrow * 64 + 32 + lk * 8);

  const u16* Kbase = Kb + (size_t)bh * (4096 * 64);
  const u16* Vbase = Vt + (size_t)bh * (64 * 4096);
  const int* mp = mask + b * 4096;

  float m_r[4], l_r[4];
#pragma unroll
  for (int r = 0; r < 4; r++) { m_r[r] = -__builtin_inff(); l_r[r] = 0.f; }
  f32x4 o[4] = {};

  for (int kt = 0; kt < 4096; kt += 64) {
    // ---- scores: S = Q * K^T  (16 q-rows x 64 keys per wave)
    f32x4 sacc[4];
#pragma unroll
    for (int cb = 0; cb < 4; cb++) {
      const u16* Kp = Kbase + (size_t)(kt + cb * 16 + lrow) * 64 + lk * 8;
      bf16x8 bk0 = *reinterpret_cast<const bf16x8*>(Kp);
      bf16x8 bk1 = *reinterpret_cast<const bf16x8*>(Kp + 32);
      f32x4 t = {};
      t = __builtin_amdgcn_mfma_f32_16x16x32_bf16(aq0, bk0, t, 0, 0, 0);
      t = __builtin_amdgcn_mfma_f32_16x16x32_bf16(aq1, bk1, t, 0, 0, 0);
      sacc[cb] = t;
    }
    // ---- scale + mask (mask per key; exact -1e9 like reference)
    float sc[4][4];
#pragma unroll
    for (int cb = 0; cb < 4; cb++) {
      int mk = mp[kt + cb * 16 + lrow];
#pragma unroll
      for (int r = 0; r < 4; r++)
        sc[cb][r] = (mk == 0) ? -1.0e9f : sacc[cb][r] * 0.125f;
    }
    // ---- online softmax per q-row (row = lk*4+r lives in the 16-lane group lk)
#pragma unroll
    for (int r = 0; r < 4; r++) {
      float vmax = fmaxf(fmaxf(sc[0][r], sc[1][r]), fmaxf(sc[2][r], sc[3][r]));
      vmax = fmaxf(vmax, __shfl_xor(vmax, 1, 16));
      vmax = fmaxf(vmax, __shfl_xor(vmax, 2, 16));
      vmax = fmaxf(vmax, __shfl_xor(vmax, 4, 16));
      vmax = fmaxf(vmax, __shfl_xor(vmax, 8, 16));
      float mnew = fmaxf(m_r[r], vmax);
      float fac = __expf(m_r[r] - mnew);   // -inf -> 0 on first tile
      float lsum = 0.f;
#pragma unroll
      for (int cb = 0; cb < 4; cb++) {
        float p = __expf(sc[cb][r] - mnew);
        lsum += p;
        p_lds[w][lk * 4 + r][cb * 16 + lrow] = f2bf(p);
      }
      lsum += __shfl_xor(lsum, 1, 16);
      lsum += __shfl_xor(lsum, 2, 16);
      lsum += __shfl_xor(lsum, 4, 16);
      lsum += __shfl_xor(lsum, 8, 16);
      l_r[r] = l_r[r] * fac + lsum;
      m_r[r] = mnew;
#pragma unroll
      for (int nb = 0; nb < 4; nb++) o[nb][r] *= fac;
    }
    // ---- PV: O += P * V   (P A-frags from LDS; V^T B-frags straight from global)
    bf16x8 ap0 = *reinterpret_cast<bf16x8*>(&p_lds[w][lrow][lk * 8]);
    bf16x8 ap1 = *reinterpret_cast<bf16x8*>(&p_lds[w][lrow][32 + lk * 8]);
#pragma unroll
    for (int nb = 0; nb < 4; nb++) {
      const u16* Vp = Vbase + (size_t)(nb * 16 + lrow) * 4096 + kt + lk * 8;
      bf16x8 bv0 = *reinterpret_cast<const bf16x8*>(Vp);
      bf16x8 bv1 = *reinterpret_cast<const bf16x8*>(Vp + 32);
      o[nb] = __builtin_amdgcn_mfma_f32_16x16x32_bf16(ap0, bv0, o[nb], 0, 0, 0);
      o[nb] = __builtin_amdgcn_mfma_f32_16x16x32_bf16(ap1, bv1, o[nb], 0, 0, 0);
    }
  }
  // ---- normalize + write attn output in [B][S][H*64] bf16 for the final GEMM
#pragma unroll
  for (int r = 0; r < 4; r++) {
    float inv = 1.0f / l_r[r];
    int srow = q0 + w * 16 + lk * 4 + r;
#pragma unroll
    for (int nb = 0; nb < 4; nb++) {
      int col = h * 64 + nb * 16 + lrow;
      AO[(size_t)(b * 4096 + srow) * 512 + col] = f2bf(o[nb][r] * inv);
    }
  }
}

extern "C" void kernel_launch(void* const* d_in, const int* in_sizes, int n_in,
                              void* d_out, int out_size, void* d_ws, size_t ws_size,
                              hipStream_t stream) {
  const float* q  = (const float*)d_in[0];
  const float* k  = (const float*)d_in[1];
  const float* v  = (const float*)d_in[2];
  const int* mask = (const int*)d_in[3];
  const float* wq = (const float*)d_in[4];
  const float* wk = (const float*)d_in[5];
  const float* wv = (const float*)d_in[6];
  const float* wo = (const float*)d_in[7];
  float* out = (float*)d_out;

  // workspace layout (u16 elements)
  u16* ws = (u16*)d_ws;
  u16* Xb = ws;                         // 3 * 8192*512
  u16* Wb = Xb + (size_t)3 * 4194304;   // 4 * 512*512 (wq,wk,wv,wo)
  u16* Qb = Wb + (size_t)4 * 262144;    // [B][H][S][64]
  u16* Kb = Qb + 4194304;               // [B][H][S][64]
  u16* Vt = Kb + 4194304;               // [B][H][64][S]
  u16* AO = Vt + 4194304;               // [B*S][512]

  // fp32 -> bf16 conversions
  cvt_f32_bf16<<<4096, 256, 0, stream>>>(q, Xb,               1048576);
  cvt_f32_bf16<<<4096, 256, 0, stream>>>(k, Xb + 4194304,     1048576);
  cvt_f32_bf16<<<4096, 256, 0, stream>>>(v, Xb + 2 * 4194304, 1048576);
  cvt_f32_bf16<<<256, 256, 0, stream>>>(wq, Wb,               65536);
  cvt_f32_bf16<<<256, 256, 0, stream>>>(wk, Wb + 262144,      65536);
  cvt_f32_bf16<<<256, 256, 0, stream>>>(wv, Wb + 2 * 262144,  65536);
  cvt_f32_bf16<<<256, 256, 0, stream>>>(wo, Wb + 3 * 262144,  65536);

  // Q/K/V projections (fused in one launch via grid.z)
  proj_gemm<<<dim3(64, 4, 3), 256, 0, stream>>>(Xb, Wb, Qb, Kb, Vt);

  // flash attention
  attn_kernel<<<dim3(64, 16), 256, 0, stream>>>(Qb, Kb, Vt, mask, AO);

  // output projection
  out_gemm<<<dim3(64, 4), 256, 0, stream>>>(AO, Wb + 3 * 262144, out);
}